// Round 1
// baseline (230.254 us; speedup 1.0000x reference)
//
#include <hip/hip_runtime.h>

#define N_NODES 50000
#define N_EDGES 800000
#define F 128
#define BN_EPS 1e-5f
#define SLOPE 0.22916666666666666f  // RReLU eval slope 11/48

#define NBKT 196          // coarse buckets (tgt>>8)
#define BKT_CAP 8192      // staging slots per bucket (mean 4082)
#define P1_CHUNK 4096
#define P1_EPB 16
#define P1_BLKS 196       // ceil(N_EDGES/P1_CHUNK)
#define CASTX_BLKS 6250   // N_NODES*F/4/256 (exact)
#define CASTW_BLKS 64
#define BKT_FINAL_CAP 9984   // cnt_max + 256*7 pad slack; 39.9 KB LDS
#define REC_CAP 1160192      // 800000 + 196*1792 + slack (pad-to-8)
#define N_RT 3125         // N_NODES/16 row-tiles (exact)
#define NPART 8           // BN-stat partial arrays (atomic contention relief)

typedef __attribute__((ext_vector_type(8))) short bf16x8;
typedef __attribute__((ext_vector_type(4))) float f32x4;
typedef unsigned long long u64;

__device__ __forceinline__ float bf2f(ushort u) {
    union { uint i; float f; } v; v.i = (uint)u << 16; return v.f;
}
__device__ __forceinline__ ushort f2bf(float f) {
    union { float f; uint i; } v; v.f = f;
    uint r = v.i + 0x7fffu + ((v.i >> 16) & 1u);  // RNE
    return (ushort)(r >> 16);
}

// ============ s1p: sort pass 1 (bucket binning) + x/W bf16 casts, one launch ============
// staging record: bits[0:31] = src | bf16(w)<<16 ; bits[32:63] = tgt
__global__ __launch_bounds__(256) void s1p_k(const int* __restrict__ src,
        const int* __restrict__ tgt, const float* __restrict__ ew,
        int* __restrict__ bcur, u64* __restrict__ stg,
        const float* __restrict__ x, ushort* __restrict__ xb,
        const float* __restrict__ W1r, const float* __restrict__ W1t,
        const float* __restrict__ W2r, const float* __restrict__ W2t,
        ushort* __restrict__ wb) {
    const int b = blockIdx.x;
    if (b >= P1_BLKS) {
        if (b < P1_BLKS + CASTX_BLKS) {
            int i = (b - P1_BLKS) * 256 + threadIdx.x;
            float4 v = reinterpret_cast<const float4*>(x)[i];
            ushort4 o;
            o.x = f2bf(v.x); o.y = f2bf(v.y); o.z = f2bf(v.z); o.w = f2bf(v.w);
            reinterpret_cast<ushort4*>(xb)[i] = o;
        } else {
            int i = (b - P1_BLKS - CASTX_BLKS) * 256 + threadIdx.x;  // 16384 total
            int m = i >> 12;
            int j = i & 4095;
            const float* sp = (m == 0) ? W1r : (m == 1) ? W1t : (m == 2) ? W2r : W2t;
            float4 v = reinterpret_cast<const float4*>(sp)[j];
            ushort4 o;
            o.x = f2bf(v.x); o.y = f2bf(v.y); o.z = f2bf(v.z); o.w = f2bf(v.w);
            reinterpret_cast<ushort4*>(wb)[i] = o;
        }
        return;
    }
    // ---- sort pass 1 ----
    __shared__ uint cnt[256];
    __shared__ uint base[256];
    __shared__ uint lcur[256];
    __shared__ uint gbase[256];
    __shared__ u64 lrec[P1_CHUNK];  // 32 KB

    const int e0 = b * P1_CHUNK;
    const int nE = min(P1_CHUNK, N_EDGES - e0);
    cnt[threadIdx.x] = 0;
    __syncthreads();

    u64 myrec[P1_EPB];
    bool myok[P1_EPB];
#pragma unroll
    for (int k = 0; k < P1_EPB; ++k) {
        int idx = threadIdx.x + (k << 8);
        bool ok = idx < nE;
        myok[k] = ok;
        if (ok) {
            int e = e0 + idx;
            uint t = (uint)tgt[e];
            uint lo = (uint)(ushort)src[e] | ((uint)f2bf(ew[e]) << 16);
            myrec[k] = (u64)lo | ((u64)t << 32);
            atomicAdd(&cnt[t >> 8], 1u);
        }
    }
    __syncthreads();
    uint v = cnt[threadIdx.x];
    base[threadIdx.x] = v;
    __syncthreads();
    for (int o = 1; o < 256; o <<= 1) {
        uint t = (threadIdx.x >= (unsigned)o) ? base[threadIdx.x - o] : 0;
        __syncthreads();
        base[threadIdx.x] += t;
        __syncthreads();
    }
    uint excl = base[threadIdx.x] - v;
    base[threadIdx.x] = excl;
    lcur[threadIdx.x] = excl;
    if (threadIdx.x < NBKT && v > 0)
        gbase[threadIdx.x] = (uint)threadIdx.x * BKT_CAP +
                             (uint)atomicAdd(&bcur[threadIdx.x], (int)v);
    __syncthreads();
#pragma unroll
    for (int k = 0; k < P1_EPB; ++k) {
        if (myok[k]) {
            uint bb = (uint)(myrec[k] >> 40);
            uint slot = atomicAdd(&lcur[bb], 1u);
            lrec[slot] = myrec[k];
        }
    }
    __syncthreads();
    for (int s = threadIdx.x; s < nE; s += 256) {
        u64 r = lrec[s];
        uint bb = (uint)(r >> 40);
        stg[gbase[bb] + ((uint)s - base[bb])] = r;
    }
}

// ============ sort pass 2: per bucket -> final recs (pad-8, zero filler) via LDS ====
__global__ __launch_bounds__(256) void sort2_k(const int* __restrict__ bcur,
        const u64* __restrict__ stg, uint* __restrict__ recs, int2* __restrict__ rng) {
    __shared__ int lcnt[256];
    __shared__ int lcur[256];
    __shared__ int sc[256];
    __shared__ int fbase_s;
    __shared__ uint lrec[BKT_FINAL_CAP];  // 39.9 KB
    const int b = blockIdx.x;
    const int tid = threadIdx.x;

    // redundant per-block scan of bucket strides -> this bucket's final base
    int cnt_t = (tid < NBKT) ? bcur[tid] : 0;
    int stride_t = (tid < NBKT) ? (((cnt_t + 7) & ~7) + 1792) : 0;
    sc[tid] = stride_t;
    lcnt[tid] = 0;
    __syncthreads();
    for (int o = 1; o < 256; o <<= 1) {
        int t = (tid >= o) ? sc[tid - o] : 0;
        __syncthreads();
        sc[tid] += t;
        __syncthreads();
    }
    if (tid == b) fbase_s = sc[tid] - stride_t;  // exclusive
    __syncthreads();
    const int fbase = fbase_s;
    const int cnt = bcur[b];
    const u64* sb = stg + (size_t)b * BKT_CAP;

    // per-node counts
    for (int i = tid; i < cnt; i += 256)
        atomicAdd(&lcnt[(int)(sb[i] >> 32) & 255], 1);
    __syncthreads();
    const int node = b * 256 + tid;
    int myc = lcnt[tid];
    int myp = (myc + 7) & ~7;            // pad to x8 (zero filler = exact no-op)
    if (node >= N_NODES) myp = 0;
    sc[tid] = myp;
    __syncthreads();
    for (int o = 1; o < 256; o <<= 1) {
        int t = (tid >= o) ? sc[tid - o] : 0;
        __syncthreads();
        sc[tid] += t;
        __syncthreads();
    }
    const int myoff = sc[tid] - myp;     // exclusive local offset
    const int ptot = sc[255];            // total padded slots this bucket
    lcur[tid] = myoff;
    if (node < N_NODES) rng[node] = make_int2(fbase + myoff, fbase + myoff + myp);
    // zero-fill (filler records: src=0, w=+0)
    for (int i = tid; i < ptot; i += 256) lrec[i] = 0;
    __syncthreads();
    // place records
    for (int i = tid; i < cnt; i += 256) {
        u64 r = sb[i];
        int n = (int)(r >> 32) & 255;
        int p = atomicAdd(&lcur[n], 1);
        lrec[p] = (uint)r;
    }
    __syncthreads();
    // coalesced dump
    for (int i = tid; i < ptot; i += 256) recs[fbase + i] = lrec[i];
}

// ============ fused gather + dual-GEMM (one block = one 16-row tile) ============
// LAYER 1: gather(featb=xb) -> LDS; GEMM(+bias); write bf16 h to outh; partial BN stats.
// LAYER 2: finalize BN scale/shift per block; gather applies BN+RReLU per element;
//          T operand applies BN+RReLU per fragment; GEMM(+bias); write fp32 to outf.
template <int LAYER>
__global__ __launch_bounds__(256) void fused_k(
        const ushort* __restrict__ featb, const int2* __restrict__ rng,
        const uint* __restrict__ recs, const ushort* __restrict__ Wr,
        const ushort* __restrict__ Wt, const float* __restrict__ bias,
        const float* __restrict__ gamma, const float* __restrict__ beta,
        float* __restrict__ Sp, float* __restrict__ S2p,
        ushort* __restrict__ outh, float* __restrict__ outf) {
    __shared__ __align__(16) uint aggu[16 * 64];   // 16 rows x 128 bf16, XOR-swizzled
    __shared__ __align__(16) float scs[128];
    __shared__ __align__(16) float shs[128];

    const int tid = threadIdx.x;
    const int lane = tid & 63;
    const int wave = tid >> 6;
    const int row0 = blockIdx.x * 16;

    if (LAYER == 2) {
        // BN finalize: sum NPART partials -> per-feature scale/shift
        if (tid < 128) {
            float s = 0.f, q = 0.f;
#pragma unroll
            for (int p = 0; p < NPART; ++p) {
                s += Sp[p * 128 + tid];
                q += S2p[p * 128 + tid];
            }
            float mean = s * (1.f / N_NODES);
            float var = q * (1.f / N_NODES) - mean * mean;
            float inv = rsqrtf(var + BN_EPS);
            float sc = gamma[tid] * inv;
            scs[tid] = sc;
            shs[tid] = beta[tid] - mean * sc;
        }
        __syncthreads();
    }

    // ---- phase 1: each wave gathers 4 nodes into LDS (bf16, swizzled) ----
    const int lane2 = lane * 2;
    float lsc0 = 1.f, lsh0 = 0.f, lsc1 = 1.f, lsh1 = 0.f;
    if (LAYER == 2) {
        lsc0 = scs[lane2]; lsh0 = shs[lane2];
        lsc1 = scs[lane2 + 1]; lsh1 = shs[lane2 + 1];
    }

#pragma unroll
    for (int i = 0; i < 4; ++i) {
        const int r = wave * 4 + i;               // local row 0..15
        const int2 rr = rng[row0 + r];
        float a0 = 0.f, a1 = 0.f;
        for (int p = rr.x; p < rr.y; p += 8) {
            uint4 ra = *reinterpret_cast<const uint4*>(recs + p);
            uint4 rb = *reinterpret_cast<const uint4*>(recs + p + 4);
            uint u0 = *reinterpret_cast<const uint*>(featb + (size_t)(ra.x & 0xffffu) * F + lane2);
            uint u1 = *reinterpret_cast<const uint*>(featb + (size_t)(ra.y & 0xffffu) * F + lane2);
            uint u2 = *reinterpret_cast<const uint*>(featb + (size_t)(ra.z & 0xffffu) * F + lane2);
            uint u3 = *reinterpret_cast<const uint*>(featb + (size_t)(ra.w & 0xffffu) * F + lane2);
            uint u4 = *reinterpret_cast<const uint*>(featb + (size_t)(rb.x & 0xffffu) * F + lane2);
            uint u5 = *reinterpret_cast<const uint*>(featb + (size_t)(rb.y & 0xffffu) * F + lane2);
            uint u6 = *reinterpret_cast<const uint*>(featb + (size_t)(rb.z & 0xffffu) * F + lane2);
            uint u7 = *reinterpret_cast<const uint*>(featb + (size_t)(rb.w & 0xffffu) * F + lane2);
            float w0 = bf2f((ushort)(ra.x >> 16)), w1 = bf2f((ushort)(ra.y >> 16));
            float w2 = bf2f((ushort)(ra.z >> 16)), w3 = bf2f((ushort)(ra.w >> 16));
            float w4 = bf2f((ushort)(rb.x >> 16)), w5 = bf2f((ushort)(rb.y >> 16));
            float w6 = bf2f((ushort)(rb.z >> 16)), w7 = bf2f((ushort)(rb.w >> 16));
            auto proc = [&](uint u, float w) {
                float t0 = bf2f((ushort)u);
                float t1 = bf2f((ushort)(u >> 16));
                if (LAYER == 2) {
                    t0 = t0 * lsc0 + lsh0; t0 = fmaxf(t0, t0 * SLOPE);
                    t1 = t1 * lsc1 + lsh1; t1 = fmaxf(t1, t1 * SLOPE);
                }
                a0 += w * t0;
                a1 += w * t1;
            };
            proc(u0, w0); proc(u1, w1); proc(u2, w2); proc(u3, w3);
            proc(u4, w4); proc(u5, w5); proc(u6, w6); proc(u7, w7);
        }
        // XOR-swizzled store: byte ^= (row&7)<<4  <=>  uint-idx ^= (row&7)<<2
        aggu[(r * 64 + lane) ^ ((r & 7) << 2)] =
            (uint)f2bf(a0) | ((uint)f2bf(a1) << 16);
    }
    __syncthreads();

    // ---- phase 2: dual GEMM, A(R) from LDS, A(T) from global, W from global (L2-hot) ----
    const int quad = lane >> 4;
    const int l16 = lane & 15;
    const int cb = wave * 32;
    const float bias0 = bias[cb + l16];
    const float bias1 = bias[cb + 16 + l16];

    f32x4 acc0 = {0.f, 0.f, 0.f, 0.f};
    f32x4 acc1 = {0.f, 0.f, 0.f, 0.f};

#pragma unroll
    for (int s = 0; s < 4; ++s) {
        const int k0 = s * 32 + quad * 8;
        const int ai = (l16 * 64 + (k0 >> 1)) ^ ((l16 & 7) << 2);
        bf16x8 aR = *reinterpret_cast<const bf16x8*>(&aggu[ai]);
        bf16x8 w0 = *reinterpret_cast<const bf16x8*>(Wr + (cb + l16) * F + k0);
        bf16x8 w1 = *reinterpret_cast<const bf16x8*>(Wr + (cb + 16 + l16) * F + k0);
        acc0 = __builtin_amdgcn_mfma_f32_16x16x32_bf16(aR, w0, acc0, 0, 0, 0);
        acc1 = __builtin_amdgcn_mfma_f32_16x16x32_bf16(aR, w1, acc1, 0, 0, 0);
    }
#pragma unroll
    for (int s = 0; s < 4; ++s) {
        const int k0 = s * 32 + quad * 8;
        bf16x8 aT = *reinterpret_cast<const bf16x8*>(featb + (size_t)(row0 + l16) * F + k0);
        if (LAYER == 2) {
#pragma unroll
            for (int e = 0; e < 8; ++e) {
                float t = bf2f((ushort)aT[e]) * scs[k0 + e] + shs[k0 + e];
                t = fmaxf(t, t * SLOPE);
                aT[e] = (short)f2bf(t);
            }
        }
        bf16x8 w0 = *reinterpret_cast<const bf16x8*>(Wt + (cb + l16) * F + k0);
        bf16x8 w1 = *reinterpret_cast<const bf16x8*>(Wt + (cb + 16 + l16) * F + k0);
        acc0 = __builtin_amdgcn_mfma_f32_16x16x32_bf16(aT, w0, acc0, 0, 0, 0);
        acc1 = __builtin_amdgcn_mfma_f32_16x16x32_bf16(aT, w1, acc1, 0, 0, 0);
    }

    // ---- epilogue: C layout col=lane&15, row=quad*4+reg ----
    const int rbase = row0 + quad * 4;
    if (LAYER == 1) {
        float s0 = 0.f, q0 = 0.f, s1 = 0.f, q1 = 0.f;
#pragma unroll
        for (int g = 0; g < 4; ++g) {
            float v0 = acc0[g] + bias0;
            float v1 = acc1[g] + bias1;
            outh[(size_t)(rbase + g) * F + cb + l16] = f2bf(v0);
            outh[(size_t)(rbase + g) * F + cb + 16 + l16] = f2bf(v1);
            s0 += v0; q0 += v0 * v0;
            s1 += v1; q1 += v1 * v1;
        }
        s0 += __shfl_down(s0, 32); s0 += __shfl_down(s0, 16);
        q0 += __shfl_down(q0, 32); q0 += __shfl_down(q0, 16);
        s1 += __shfl_down(s1, 32); s1 += __shfl_down(s1, 16);
        q1 += __shfl_down(q1, 32); q1 += __shfl_down(q1, 16);
        if (lane < 16) {
            float* Sb = Sp + (size_t)(blockIdx.x & (NPART - 1)) * 128;
            float* S2b = S2p + (size_t)(blockIdx.x & (NPART - 1)) * 128;
            unsafeAtomicAdd(&Sb[cb + lane], s0);
            unsafeAtomicAdd(&S2b[cb + lane], q0);
            unsafeAtomicAdd(&Sb[cb + 16 + lane], s1);
            unsafeAtomicAdd(&S2b[cb + 16 + lane], q1);
        }
    } else {
#pragma unroll
        for (int g = 0; g < 4; ++g) {
            outf[(size_t)(rbase + g) * F + cb + l16] = acc0[g] + bias0;
            outf[(size_t)(rbase + g) * F + cb + 16 + l16] = acc1[g] + bias1;
        }
    }
}

extern "C" void kernel_launch(void* const* d_in, const int* in_sizes, int n_in,
                              void* d_out, int out_size, void* d_ws, size_t ws_size,
                              hipStream_t stream) {
    const float* x     = (const float*)d_in[0];
    const int*   ei    = (const int*)d_in[1];
    const float* ea    = (const float*)d_in[2];
    const float* W1r   = (const float*)d_in[3];
    const float* b1    = (const float*)d_in[4];
    const float* W1t   = (const float*)d_in[5];
    const float* gamma = (const float*)d_in[6];
    const float* beta  = (const float*)d_in[7];
    const float* W2r   = (const float*)d_in[8];
    const float* b2    = (const float*)d_in[9];
    const float* W2t   = (const float*)d_in[10];
    float* out = (float*)d_out;

    char* ws = (char*)d_ws;
    size_t off = 0;
    u64*    stg   = (u64*)(ws + off);    off += (size_t)NBKT * BKT_CAP * 8;  // 12.85 MB
    ushort* featb = (ushort*)(ws + off); off += (size_t)N_NODES * F * 2;     // 12.8 MB (xb)
    uint*   recs  = (uint*)(ws + off);   off += (size_t)REC_CAP * 4;         // 4.6 MB (no memset)
    int*    bcur  = (int*)(ws + off);    off += 256 * 4;                     // memset 0
    float*  Sp    = (float*)(ws + off);  off += NPART * 128 * 4;             // memset 0
    float*  S2p   = (float*)(ws + off);  off += NPART * 128 * 4;             // memset 0
    int2*   rng   = (int2*)(ws + off);   off += (size_t)N_NODES * 8;         // 400 KB
    ushort* wb    = (ushort*)(ws + off); off += 4 * 16384 * 2;               // 128 KB
    ushort* hraw  = (ushort*)stg;        // aliases stg (dead after sort2); bf16 h (12.8 MB)

    const int* srcp = ei;
    const int* tgtp = ei + N_EDGES;

    // tiny memset: bcur (cursors) + Sp/S2p (partial stats)
    hipMemsetAsync(bcur, 0, 256 * 4 + 2 * NPART * 128 * 4, stream);
    s1p_k<<<P1_BLKS + CASTX_BLKS + CASTW_BLKS, 256, 0, stream>>>(
        srcp, tgtp, ea, bcur, stg, x, featb, W1r, W1t, W2r, W2t, wb);
    sort2_k<<<NBKT, 256, 0, stream>>>(bcur, stg, recs, rng);

    // ---- layer 1: fused gather+GEMM (+partial BN stats), bf16 h into stg region ----
    fused_k<1><<<N_RT, 256, 0, stream>>>(featb, rng, recs, wb, wb + 16384, b1,
                                         gamma, beta, Sp, S2p, hraw, out);
    // ---- layer 2: fused BN-finalize + act + gather+GEMM, fp32 out ----
    fused_k<2><<<N_RT, 256, 0, stream>>>(hraw, rng, recs, wb + 32768, wb + 49152, b2,
                                         gamma, beta, Sp, S2p, hraw, out);
}